// Round 9
// baseline (382.460 us; speedup 1.0000x reference)
//
#include <hip/hip_runtime.h>
#include <hip/hip_bf16.h>

#define OMEGA0 30.0f
#define IN_DIM 512
#define OUT_DIM 512
#define BM 64
#define THREADS 512

typedef _Float16 f16;
typedef __attribute__((ext_vector_type(2))) __fp16 fp16x2;   // cvt_pkrtz return type
typedef __attribute__((ext_vector_type(8))) _Float16 f16x8;
typedef __attribute__((ext_vector_type(4))) float f32x4;
typedef __attribute__((ext_vector_type(16))) float f32x16;

// ---------------- pre-kernel 1: thetaW windows for 32x32x16 B-frags ----------------
// Window widB = cg*32 + kk (cg 0..15 col-groups of 32 cols, kk 0..31 k-steps of 16).
// Lane l elem e: thetaW[widB*512 + l*8 + e] = f16(30*theta[col][k+e]),
//   col = cg*32 + (l&31), k = kk*16 + (l>>5)*8.
// A wave's B-fragment read is a contiguous 1KB burst (L2-friendly).
__global__ void make_thetaW_kernel(const float* __restrict__ theta, f16* __restrict__ thetaW) {
    int t = threadIdx.x, w = t >> 6, lane = t & 63;
    int wid = blockIdx.x * 4 + w;            // 0..511
    int kk = wid & 31, cg = wid >> 5;
    int col = cg * 32 + (lane & 31);
    int k   = kk * 16 + (lane >> 5) * 8;
    const float* src = theta + (long)col * IN_DIM + k;
    f32x4 a = *(const f32x4*)src;
    f32x4 b = *(const f32x4*)(src + 4);
    f16x8 o;
#pragma unroll
    for (int i = 0; i < 4; i++) { o[i] = (f16)(OMEGA0 * a[i]); o[4 + i] = (f16)(OMEGA0 * b[i]); }
    *(f16x8*)&thetaW[(long)wid * 512 + lane * 8] = o;
}

// ---------------- pre-kernel 2: bias[o] = 30*sum_k theta[o][k] + phi[o] ----------------
__global__ void make_bias_kernel(const float* __restrict__ theta, const float* __restrict__ phi,
                                 float* __restrict__ bias) {
    int w = threadIdx.x >> 6, lane = threadIdx.x & 63;
    int o = blockIdx.x * 4 + w;
    const float* row = theta + (long)o * IN_DIM + lane * 8;
    f32x4 a = *(const f32x4*)row;
    f32x4 b = *(const f32x4*)(row + 4);
    float s = a[0] + a[1] + a[2] + a[3] + b[0] + b[1] + b[2] + b[3];
#pragma unroll
    for (int off = 32; off; off >>= 1) s += __shfl_down(s, off, 64);
    if (lane == 0) bias[o] = OMEGA0 * s + phi[o];
}

// ---------------- main: A-resident GEMM + cos epilogue ----------------
// Block owns BM=64 rows and ALL 512 output cols -> x read EXACTLY ONCE from HBM.
// Stage: x rows -> f16 A-windows in LDS (window id = fr*32+kk, fr 0..1, kk 0..31;
// lane l holds A[row=fr*32+(l&31)][k=kk*16+(l>>5)*8 ..+8]). Every LDS write and
// read is a full-window 64-lane contiguous burst -> zero bank conflicts.
// Compute: 8 waves x 2 col-groups each; per (cg,kk): 2 ds_read_b128 (A frags),
// 1 global 1KB B-window read (depth-4 ring), 2 x mfma_f32_32x32x16_f16.
// 64KB LDS -> 2 blocks/CU; staggered blocks overlap stage with compute.
__launch_bounds__(THREADS, 2)
__global__ void siren_gemm_kernel(const float* __restrict__ x, const f16* __restrict__ thetaW,
                                  const float* __restrict__ bias, float* __restrict__ out) {
    __shared__ f16 ldsA[BM * IN_DIM];   // 64 windows x 1KB = 64 KB

    long m0 = (long)blockIdx.x * BM;
    int t = threadIdx.x, w = t >> 6, lane = t & 63;

    // ---- stage: wave w fills windows w*8 .. w*8+7 ----
#pragma unroll
    for (int j = 0; j < 8; ++j) {
        int id = w * 8 + j;              // fr = id>>5, kk = id&31
        int fr = id >> 5, kk = id & 31;
        int row = fr * 32 + (lane & 31);
        int k   = kk * 16 + (lane >> 5) * 8;
        const float* p = x + (m0 + row) * (long)IN_DIM + k;
        f32x4 a = *(const f32x4*)p;
        f32x4 b = *(const f32x4*)(p + 4);
        union { fp16x2 h[4]; f16x8 v; } u;
        u.h[0] = __builtin_amdgcn_cvt_pkrtz(a[0], a[1]);
        u.h[1] = __builtin_amdgcn_cvt_pkrtz(a[2], a[3]);
        u.h[2] = __builtin_amdgcn_cvt_pkrtz(b[0], b[1]);
        u.h[3] = __builtin_amdgcn_cvt_pkrtz(b[2], b[3]);
        *(f16x8*)&ldsA[id * 512 + lane * 8] = u.v;
    }
    __syncthreads();   // the only barrier

    // ---- compute: wave w handles col-groups w and w+8 ----
#pragma unroll 1
    for (int g = 0; g < 2; ++g) {
        int cg = w + g * 8;
        const f16* bw = thetaW + (long)(cg * 32) * 512 + lane * 8;   // + kk*512
        float bv = bias[cg * 32 + (lane & 31)];

        f32x16 acc0 = {};
        f32x16 acc1 = {};
        f16x8 br[4];                    // depth-4 B ring (static idx after unroll)
#pragma unroll
        for (int s = 0; s < 4; ++s) br[s] = *(const f16x8*)&bw[s * 512];

#pragma unroll
        for (int kk = 0; kk < 32; ++kk) {
            f16x8 a0 = *(const f16x8*)&ldsA[kk * 512 + lane * 8];
            f16x8 a1 = *(const f16x8*)&ldsA[(32 + kk) * 512 + lane * 8];
            acc0 = __builtin_amdgcn_mfma_f32_32x32x16_f16(a0, br[kk & 3], acc0, 0, 0, 0);
            acc1 = __builtin_amdgcn_mfma_f32_32x32x16_f16(a1, br[kk & 3], acc1, 0, 0, 0);
            if (kk + 4 < 32)
                br[kk & 3] = *(const f16x8*)&bw[(kk + 4) * 512];
        }

        // ---- epilogue: cos(acc + bias[col]) ----
        int colo = cg * 32 + (lane & 31);
#pragma unroll
        for (int r = 0; r < 16; ++r) {
            int rrow = (r & 3) + 8 * (r >> 2) + 4 * (lane >> 5);
            out[(m0 + rrow) * OUT_DIM + colo]      = __cosf(acc0[r] + bv);
            out[(m0 + 32 + rrow) * OUT_DIM + colo] = __cosf(acc1[r] + bv);
        }
    }
}

extern "C" void kernel_launch(void* const* d_in, const int* in_sizes, int n_in,
                              void* d_out, int out_size, void* d_ws, size_t ws_size,
                              hipStream_t stream) {
    const float* x     = (const float*)d_in[0];
    const float* theta = (const float*)d_in[1];
    const float* phi   = (const float*)d_in[2];
    float* out = (float*)d_out;

    size_t thetaW_bytes = (size_t)512 * 512 * sizeof(f16);      // 512 KB (512 windows x 1KB)
    size_t need = thetaW_bytes + OUT_DIM * sizeof(float);       // + 2 KB bias
    if (ws_size < need) return;

    f16*   thetaW = (f16*)d_ws;
    float* bias   = (float*)((char*)d_ws + thetaW_bytes);

    int Brows = in_sizes[0] / IN_DIM;  // 131072

    make_thetaW_kernel<<<128, 256, 0, stream>>>(theta, thetaW);
    make_bias_kernel<<<OUT_DIM / 4, 256, 0, stream>>>(theta, phi, bias);

    int grid = Brows / BM;  // 2048
    siren_gemm_kernel<<<grid, THREADS, 0, stream>>>(x, thetaW, bias, out);
}